// Round 10
// baseline (202.410 us; speedup 1.0000x reference)
//
#include <hip/hip_runtime.h>

typedef unsigned short u16;
typedef unsigned int u32;
typedef __attribute__((ext_vector_type(8))) short short8;
typedef __attribute__((ext_vector_type(4))) float f32x4;

#define BB 8
#define CCH 256
#define HH 64
#define WW 64
#define HP 66
#define NPOS 4096
#define KTOT 2304

// ---- ws layout (bytes) ----
#define XT_BYTES   17842176ull                 // bf16 [8][66][66][256]
#define W2R_OFF    17842176ull                 // bf16 1.18MB: FRAGMENT layout [36gs][2j][4wr][4ao][64lane][8e]
#define WOFF2_OFF  19021824ull                 // bf16 [32][2304] (row-major, k_off2)
#define OFF2_OFF   40402944ull                 // float2 [8][9][4096]
#define WS_MIN     42762240ull

__device__ __forceinline__ u16 f2bf(float f) {
    union { float f; u32 u; } v; v.f = f;
    u32 r = v.u + 0x7FFFu + ((v.u >> 16) & 1u);
    return (u16)(r >> 16);
}
__device__ __forceinline__ u32 pk2(float a, float b) {
    return (u32)f2bf(a) | ((u32)f2bf(b) << 16);
}
// single-instruction packed f32->bf16 (RNE, same bits as pk2 for finite values)
__device__ __forceinline__ u32 cvtpk(float lo, float hi) {
    u32 r;
    asm("v_cvt_pk_bf16_f32 %0, %1, %2" : "=v"(r) : "v"(lo), "v"(hi));
    return r;
}
__device__ __forceinline__ void bf2x2(u32 p, float& a, float& b) {
    union { u32 u; float f; } va, vb;
    va.u = p << 16; vb.u = p & 0xffff0000u;
    a = va.f; b = vb.f;
}
// async global->LDS, 16B per lane; LDS dest = wave-uniform base + lane*16
__device__ __forceinline__ void ldg_lds16(const u16* g, u16* l) {
    __builtin_amdgcn_global_load_lds((const __attribute__((address_space(1))) u32*)g,
                                     (__attribute__((address_space(3))) u32*)l, 16, 0, 0);
}

// ---- K_PRE: weight-reorder (MFMA-fragment layout, HW-verified round 9) + border-zero + transpose ----
__global__ __launch_bounds__(256) void k_pre(const float* __restrict__ w, const float* __restrict__ w_off,
                                             const float* __restrict__ x,
                                             u16* __restrict__ W2r, u16* __restrict__ Woff2,
                                             u16* __restrict__ xT) {
    __shared__ __align__(16) float SH[4608];   // prep uses 2304; transpose uses 64x72
    int bx = blockIdx.x;
    int t = threadIdx.x;
    if (bx < 256) {
        // emit W2r in MFMA-fragment order so k_gemm's A-loads are 1KB coalesced:
        // element (o=wr*64+ao*16+m, kcol=gs*64+(j*4+q)*8+e) at
        //   u16 idx = (((gs*2+j)*4+wr)*4+ao)*512 + (q*16+m)*8 + e
        int o = bx;
        const float* src = w + (size_t)o * 2304;
#pragma unroll
        for (int j = 0; j < 9; ++j) SH[j * 256 + t] = src[j * 256 + t];   // SH[ch*9+tap]
        __syncthreads();
        int m = o & 15, ao = (o >> 4) & 3, wr = o >> 6;
        for (int ci = t; ci < 288; ci += 256) {
            int gs = ci >> 3, jj = (ci >> 2) & 1, q = ci & 3;
            int kbase = gs * 64 + (jj * 4 + q) * 8;
            int tap = kbase >> 8, ch0 = kbase & 255;      // 8 contiguous ch, one tap
            uint4 sv;
            sv.x = pk2(SH[(ch0 + 0) * 9 + tap], SH[(ch0 + 1) * 9 + tap]);
            sv.y = pk2(SH[(ch0 + 2) * 9 + tap], SH[(ch0 + 3) * 9 + tap]);
            sv.z = pk2(SH[(ch0 + 4) * 9 + tap], SH[(ch0 + 5) * 9 + tap]);
            sv.w = pk2(SH[(ch0 + 6) * 9 + tap], SH[(ch0 + 7) * 9 + tap]);
            u16* dst = W2r + ((size_t)((((gs * 2 + jj) * 4 + wr) << 2) + ao) << 9)
                           + ((q * 16 + m) << 3);
            *(uint4*)dst = sv;
        }
    } else if (bx == 256) {
        for (int o2 = 0; o2 < 32; ++o2) {
            if (o2 < 18) {
                const float* src = w_off + (size_t)o2 * 2304;
#pragma unroll
                for (int j = 0; j < 9; ++j) SH[j * 256 + t] = src[j * 256 + t];
                __syncthreads();
#pragma unroll
                for (int k = 0; k < 9; ++k) Woff2[(size_t)o2 * 2304 + k * 256 + t] = f2bf(SH[t * 9 + k]);
                __syncthreads();
            } else {
#pragma unroll
                for (int k = 0; k < 9; ++k) Woff2[(size_t)o2 * 2304 + k * 256 + t] = 0;
            }
        }
    } else if (bx < 777) {
        // border zero: 2080 positions, 4 per block (64 lanes each)
        int idx = (bx - 257) * 4 + (t >> 6);
        int b = idx / 260, m = idx - b * 260;
        int y, xx;
        if (m < 66)       { y = 0;  xx = m; }
        else if (m < 132) { y = 65; xx = m - 66; }
        else if (m < 196) { y = m - 132 + 1; xx = 0; }
        else              { y = m - 196 + 1; xx = 65; }
        u16* p = xT + ((size_t)(b * HP + y) * HP + xx) * CCH + (t & 63) * 4;
        uint2 zz; zz.x = 0; zz.y = 0;
        *(uint2*)p = zz;
    } else {
        int idx = bx - 777;               // 2048 transpose tiles
        int b = idx & 7;                  // XCD pin
        int r = idx >> 3;
        int y = r & 63, c0 = (r >> 6) * 64;
        {
            int i = t >> 2, seg = t & 3;   // channel i, 16-float x-segment
            const float* src = x + (((size_t)(b * CCH + c0 + i) * HH + y) * WW) + seg * 16;
            float4 v0 = *(const float4*)(src);
            float4 v1 = *(const float4*)(src + 4);
            float4 v2 = *(const float4*)(src + 8);
            float4 v3 = *(const float4*)(src + 12);
            *(float4*)&SH[i * 72 + seg * 16]      = v0;
            *(float4*)&SH[i * 72 + seg * 16 + 4]  = v1;
            *(float4*)&SH[i * 72 + seg * 16 + 8]  = v2;
            *(float4*)&SH[i * 72 + seg * 16 + 12] = v3;
        }
        __syncthreads();
        {
            int xc = t >> 2, cs = t & 3;   // x-position xc, 16-channel segment cs
            u16* dst = xT + (((size_t)(b * HP + y + 1) * HP) + (xc + 1)) * CCH + c0 + cs * 16;
            u32 p[8];
#pragma unroll
            for (int j = 0; j < 8; ++j)
                p[j] = pk2(SH[(cs * 16 + 2 * j) * 72 + xc], SH[(cs * 16 + 2 * j + 1) * 72 + xc]);
            uint4 d0, d1;
            d0.x = p[0]; d0.y = p[1]; d0.z = p[2]; d0.w = p[3];
            d1.x = p[4]; d1.y = p[5]; d1.z = p[6]; d1.w = p[7];
            *(uint4*)dst = d0;
            *(uint4*)(dst + 8) = d1;
        }
    }
}

// ---- K_OFF2: offset conv, full K=2304 -> off2 directly (round-7 verified) ----
__global__ __launch_bounds__(256) void k_off2(const u16* __restrict__ xT,
                                              const u16* __restrict__ Woff2,
                                              const float* __restrict__ b_off,
                                              float2* __restrict__ off2) {
    __shared__ __align__(16) u16 AS[3][2048];   // [32 o-row][64 k] x3, 12KB
    __shared__ __align__(16) u16 BS[3][8192];   // [128 pos][64 k] x3, 48KB
    int b = blockIdx.x;
    int pos0 = blockIdx.y * 128;
    int t = threadIdx.x, lane = t & 63, wv = t >> 6;

    int srow = lane >> 3;
    int sw8 = ((lane & 7) ^ srow) << 3;
    const u16* pXb = xT + (size_t)b * HP * HP * CCH;

    f32x4 acc[2][2];
    f32x4 z = {0.f, 0.f, 0.f, 0.f};
    acc[0][0] = z; acc[0][1] = z; acc[1][0] = z; acc[1][1] = z;

    auto stage = [&](int gs, int d) {            // gs in [0,36): tap = gs>>2, cs = gs&3
        int t9 = gs >> 2, cs = gs & 3;
        int ky = t9 / 3, kx = t9 - (t9 / 3) * 3;
        int koff = t9 * 256 + cs * 64;           // A k-offset (Woff2 row-major [32][2304])
        {
            int row = wv * 8 + srow;
            ldg_lds16(Woff2 + (size_t)row * KTOT + koff + sw8, &AS[d][wv * 512]);
        }
#pragma unroll
        for (int i = 0; i < 4; ++i) {
            int inst = wv * 4 + i;
            int rowg = pos0 + inst * 8 + srow;
            int py_ = rowg >> 6, px_ = rowg & 63;
            const u16* g = pXb + (((size_t)(py_ + ky) * HP) + px_ + kx) * CCH + cs * 64 + sw8;
            ldg_lds16(g, &BS[d][inst * 512]);
        }
    };

    stage(0, 0);                                 // 5 loads
    stage(1, 1);                                 // 5 loads

    int m = lane & 15, q = lane >> 4, key = lane & 7;
    for (int gs = 0; gs < 36; ++gs) {
        int cur = gs % 3;
        if (gs <= 34) { asm volatile("s_waitcnt vmcnt(5)" ::: "memory"); }
        else          { asm volatile("s_waitcnt vmcnt(0)" ::: "memory"); }
        __builtin_amdgcn_s_barrier();            // stage(gs) visible; buf (gs+2)%3 free
        if (gs < 34) stage(gs + 2, (gs + 2) % 3);
#pragma unroll
        for (int j = 0; j < 2; ++j) {
            int slot8 = (((j * 4 + q) ^ key) << 3);
            short8 a0 = *(const short8*)&AS[cur][m * 64 + slot8];
            short8 a1 = *(const short8*)&AS[cur][(16 + m) * 64 + slot8];
            short8 b0 = *(const short8*)&BS[cur][(wv * 32 + m) * 64 + slot8];
            short8 b1 = *(const short8*)&BS[cur][(wv * 32 + 16 + m) * 64 + slot8];
            acc[0][0] = __builtin_amdgcn_mfma_f32_16x16x32_bf16(a0, b0, acc[0][0], 0, 0, 0);
            acc[0][1] = __builtin_amdgcn_mfma_f32_16x16x32_bf16(a0, b1, acc[0][1], 0, 0, 0);
            acc[1][0] = __builtin_amdgcn_mfma_f32_16x16x32_bf16(a1, b0, acc[1][0], 0, 0, 0);
            acc[1][1] = __builtin_amdgcn_mfma_f32_16x16x32_bf16(a1, b1, acc[1][1], 0, 0, 0);
        }
        asm volatile("s_waitcnt lgkmcnt(0)" ::: "memory");
    }

    int nn = lane & 15;
#pragma unroll
    for (int ao = 0; ao < 2; ++ao)
#pragma unroll
        for (int bn = 0; bn < 2; ++bn) {
            int pos = pos0 + wv * 32 + bn * 16 + nn;
#pragma unroll
            for (int rp = 0; rp < 2; ++rp) {
                int o = ao * 16 + q * 4 + rp * 2;
                if (o < 18) {
                    float2 v;
                    v.x = acc[ao][bn][rp * 2]     + b_off[o];
                    v.y = acc[ao][bn][rp * 2 + 1] + b_off[o + 1];
                    off2[(((size_t)(b * 9 + (o >> 1))) << 12) + pos] = v;
                }
            }
        }
}

// ---- K4 v10: round-4 schedule EXACTLY (BN=128, 36 steps, 1 barrier/step, same
// blend/gather/region rotation) with ONE change: A operand in REGISTER double-buffer
// (afA/afB), loaded from fragment-ordered W2rf one full step ahead (fixes round-9's
// same-step A-latency exposure). A's 8 ds_read_b128/step/wave disappear -> LDS pipe
// per step halves; AS LDS gone (BSF only, 67.6KB). All vmcnt compiler-managed.
__global__ __launch_bounds__(512, 2) void k_gemm(const u16* __restrict__ xT,
                                                 const float2* __restrict__ off2,
                                                 const u16* __restrict__ W2rf,
                                                 const float* __restrict__ bias,
                                                 float* __restrict__ out) {
    __shared__ __align__(16) u16 BSF[128 * 264]; // [128 pos][256 k + 8 pad], 67.6KB
    int b = blockIdx.x;                          // linear%8==b -> XCD-pinned, xT slice L2-hot
    int pos0 = blockIdx.z * 128;
    int t = threadIdx.x, lane = t & 63, wv = t >> 6;   // wv 0..7
    int wr = wv >> 1, wc = wv & 1;               // 4M x 2N wave grid, per-wave 64x64 out

    int brow0 = t >> 3;                          // 0..63
    int bcl = (t & 7) << 3;                      // 0..56 (u16 elems)
    int bbase = b * HP * HP;

    f32x4 acc[4][4];
    f32x4 z = {0.f, 0.f, 0.f, 0.f};
#pragma unroll
    for (int i = 0; i < 4; ++i)
#pragma unroll
        for (int j = 0; j < 4; ++j) acc[i][j] = z;

    // pipeline state
    const u16* gp[2][4];
    float wt[2][4];
    float2 fnext[2];
    uint4 gv[8];

    auto computeState = [&](int tap) {
#pragma unroll
        for (int ii = 0; ii < 2; ++ii) {
            int pos = pos0 + brow0 + (ii << 6);
            int y = pos >> 6, x = pos & 63;
            int ky = tap / 3, kx = tap - (tap / 3) * 3;
            float pyf = (float)(y - 1 + ky) + fnext[ii].x;
            float pxf = (float)(x - 1 + kx) + fnext[ii].y;
            float y0f = floorf(pyf), x0f = floorf(pxf);
            int y0 = (int)y0f, x0 = (int)x0f;
            int y1 = y0 + 1, x1 = x0 + 1;
            float wy1 = pyf - y0f, wy0 = 1.f - wy1;
            float wx1 = pxf - x0f, wx0 = 1.f - wx1;
            bool vy0 = (y0 >= 0) & (y0 < HH), vy1 = (y1 >= 0) & (y1 < HH);
            bool vx0 = (x0 >= 0) & (x0 < WW), vx1 = (x1 >= 0) & (x1 < WW);
            int yc0 = min(max(y0, 0), HH - 1), yc1 = min(max(y1, 0), HH - 1);
            int xc0 = min(max(x0, 0), WW - 1), xc1 = min(max(x1, 0), WW - 1);
            wt[ii][0] = (vy0 & vx0) ? wy0 * wx0 : 0.f;
            wt[ii][1] = (vy0 & vx1) ? wy0 * wx1 : 0.f;
            wt[ii][2] = (vy1 & vx0) ? wy1 * wx0 : 0.f;
            wt[ii][3] = (vy1 & vx1) ? wy1 * wx1 : 0.f;
            gp[ii][0] = xT + (size_t)(bbase + (yc0 + 1) * HP + xc0 + 1) * CCH + bcl;
            gp[ii][1] = xT + (size_t)(bbase + (yc0 + 1) * HP + xc1 + 1) * CCH + bcl;
            gp[ii][2] = xT + (size_t)(bbase + (yc1 + 1) * HP + xc0 + 1) * CCH + bcl;
            gp[ii][3] = xT + (size_t)(bbase + (yc1 + 1) * HP + xc1 + 1) * CCH + bcl;
        }
    };
    auto gatherRegion = [&](int rr) {
#pragma unroll
        for (int ii = 0; ii < 2; ++ii)
#pragma unroll
            for (int c = 0; c < 4; ++c)
                gv[ii * 4 + c] = *(const uint4*)(gp[ii][c] + rr * 64);
    };
    auto blendWrite = [&](int rr) {
#pragma unroll
        for (int ii = 0; ii < 2; ++ii) {
            int row = brow0 + (ii << 6);
            float v[8];
#pragma unroll
            for (int dw = 0; dw < 4; ++dw) {
                float a0, b0_, a1, b1_, a2, b2_, a3, b3_;
                bf2x2(((const u32*)&gv[ii * 4 + 0])[dw], a0, b0_);
                bf2x2(((const u32*)&gv[ii * 4 + 1])[dw], a1, b1_);
                bf2x2(((const u32*)&gv[ii * 4 + 2])[dw], a2, b2_);
                bf2x2(((const u32*)&gv[ii * 4 + 3])[dw], a3, b3_);
                v[2 * dw]     = wt[ii][0] * a0 + wt[ii][1] * a1 + wt[ii][2] * a2 + wt[ii][3] * a3;
                v[2 * dw + 1] = wt[ii][0] * b0_ + wt[ii][1] * b1_ + wt[ii][2] * b2_ + wt[ii][3] * b3_;
            }
            uint4 sv;
            sv.x = cvtpk(v[0], v[1]); sv.y = cvtpk(v[2], v[3]);
            sv.z = cvtpk(v[4], v[5]); sv.w = cvtpk(v[6], v[7]);
            *(uint4*)&BSF[row * 264 + rr * 64 + bcl] = sv;
        }
    };
    auto loadA = [&](int gs, short8 (&af)[8]) {  // 8 coalesced 1KB fragment loads -> registers
#pragma unroll
        for (int jj = 0; jj < 2; ++jj)
#pragma unroll
            for (int ao = 0; ao < 4; ++ao)
                af[jj * 4 + ao] = *(const short8*)(W2rf
                    + ((size_t)((((gs * 2 + jj) * 4 + wr) << 2) + ao) << 9) + (lane << 3));
    };

    short8 afA[8], afB[8];

    // ---- prologue: fill all 4 regions of tap 0 (sync); prefetch off2(1); load A(0) ----
    {
        fnext[0] = off2[((size_t)(b * 9 + 0) << 12) + pos0 + brow0];
        fnext[1] = off2[((size_t)(b * 9 + 0) << 12) + pos0 + brow0 + 64];
        computeState(0);
#pragma unroll
        for (int rr = 0; rr < 4; ++rr) {
            gatherRegion(rr);
            blendWrite(rr);
        }
        fnext[0] = off2[((size_t)(b * 9 + 1) << 12) + pos0 + brow0];
        fnext[1] = off2[((size_t)(b * 9 + 1) << 12) + pos0 + brow0 + 64];
        loadA(0, afA);
        asm volatile("s_waitcnt lgkmcnt(0)" ::: "memory");   // BSF(tap0) ds_writes flushed
    }

    int m = lane & 15, q = lane >> 4;

    // one pipeline step; cur = A-regs for this step, nxt = A-regs filled for gs+1
    auto body = [&](int gs, short8 (&cur)[8], short8 (&nxt)[8]) {
        int t9 = gs >> 2, cs = gs & 3;
        __builtin_amdgcn_s_barrier();            // BSF region cs ready; region (cs+3)&3 free

        // blend gathers issued last step -> region (cs+3)&3 (compiler waits G's vmcnt;
        // cover = MFMA(gs-1)+barrier, same as round-4)
        if (gs >= 1 && gs <= 32) blendWrite((cs + 3) & 3);
        if (cs == 0 && t9 <= 7) computeState(t9 + 1);
        if (gs <= 31) {
            if (cs == 3 && t9 <= 6) {            // prefetch off2 for tap t9+2 (used at next cs0)
                fnext[0] = off2[((size_t)(b * 9 + t9 + 2) << 12) + pos0 + brow0];
                fnext[1] = off2[((size_t)(b * 9 + t9 + 2) << 12) + pos0 + brow0 + 64];
            }
            gatherRegion(cs);                    // G(gs): in flight across next barrier
        }
        if (gs < 35) loadA(gs + 1, nxt);         // A(gs+1): full step of cover before use
        __builtin_amdgcn_sched_barrier(0);       // loads issued before MFMA block

#pragma unroll
        for (int jj = 0; jj < 2; ++jj) {
            int bchunk = (cs * 8 + jj * 4 + q) << 3;
            short8 bfr[4];
#pragma unroll
            for (int bn = 0; bn < 4; ++bn)
                bfr[bn] = *(const short8*)&BSF[(wc * 64 + bn * 16 + m) * 264 + bchunk];
            __builtin_amdgcn_s_setprio(1);
#pragma unroll
            for (int ao = 0; ao < 4; ++ao)
#pragma unroll
                for (int bn = 0; bn < 4; ++bn)
                    acc[ao][bn] = __builtin_amdgcn_mfma_f32_16x16x32_bf16(cur[jj * 4 + ao], bfr[bn], acc[ao][bn], 0, 0, 0);
            __builtin_amdgcn_s_setprio(0);
        }
        asm volatile("s_waitcnt lgkmcnt(0)" ::: "memory");  // ds reads+writes done before next barrier
    };

    for (int gs = 0; gs < 36; gs += 2) {         // static parity unroll: af regs stay in registers
        body(gs, afA, afB);
        body(gs + 1, afB, afA);
    }

    // epilogue: bias + sigmoid -> fp32 NCHW
    int nn = lane & 15;
#pragma unroll
    for (int ao = 0; ao < 4; ++ao) {
        int ob = wr * 64 + ao * 16 + q * 4;
#pragma unroll
        for (int bn = 0; bn < 4; ++bn) {
            int pos = pos0 + wc * 64 + bn * 16 + nn;
#pragma unroll
            for (int r = 0; r < 4; ++r) {
                float v = acc[ao][bn][r] + bias[ob + r];
                float sg = 1.0f / (1.0f + __expf(-v));
                out[(size_t)((b * CCH + ob + r) * NPOS) + pos] = sg;
            }
        }
    }
}

extern "C" void kernel_launch(void* const* d_in, const int* in_sizes, int n_in,
                              void* d_out, int out_size, void* d_ws, size_t ws_size,
                              hipStream_t stream) {
    const float* x     = (const float*)d_in[0];
    const float* w_off = (const float*)d_in[1];
    const float* b_off = (const float*)d_in[2];
    const float* w     = (const float*)d_in[3];
    const float* bias  = (const float*)d_in[4];
    float* out = (float*)d_out;

    char* ws = (char*)d_ws;
    u16*    xT    = (u16*)ws;
    u16*    W2r   = (u16*)(ws + W2R_OFF);
    u16*    Woff2 = (u16*)(ws + WOFF2_OFF);
    float2* off2  = (float2*)(ws + OFF2_OFF);

    if (ws_size < WS_MIN) return;

    k_pre<<<2825, 256, 0, stream>>>(w, w_off, x, W2r, Woff2, xT);
    k_off2<<<dim3(8, 32), 256, 0, stream>>>(xT, Woff2, b_off, off2);
    k_gemm<<<dim3(8, 1, 32), 512, 0, stream>>>(xT, off2, W2r, bias, out);
}

// Round 11
// 183.272 us; speedup vs baseline: 1.1044x; 1.1044x over previous
//
#include <hip/hip_runtime.h>

typedef unsigned short u16;
typedef unsigned int u32;
typedef __attribute__((ext_vector_type(8))) short short8;
typedef __attribute__((ext_vector_type(4))) float f32x4;

#define BB 8
#define CCH 256
#define HH 64
#define WW 64
#define HP 66
#define NPOS 4096
#define KTOT 2304

// ---- ws layout (bytes) ----
#define XT_BYTES   17842176ull                 // bf16 [8][66][66][256]
#define W2R_OFF    17842176ull                 // bf16 [256][2304] row-major
#define WOFF2_OFF  19021824ull                 // bf16 [32][2304]
#define P_OFF      19169280ull                 // fp32 [8][9][18][4096] partials
#define OFF2_OFF   40402944ull                 // float2 [8][9][4096]
#define WS_MIN     42762240ull

__device__ __forceinline__ u16 f2bf(float f) {
    union { float f; u32 u; } v; v.f = f;
    u32 r = v.u + 0x7FFFu + ((v.u >> 16) & 1u);
    return (u16)(r >> 16);
}
__device__ __forceinline__ u32 pk2(float a, float b) {
    return (u32)f2bf(a) | ((u32)f2bf(b) << 16);
}
// single-instruction packed f32->bf16 (RNE, same bits as pk2 for finite values)
__device__ __forceinline__ u32 cvtpk(float lo, float hi) {
    u32 r;
    asm("v_cvt_pk_bf16_f32 %0, %1, %2" : "=v"(r) : "v"(lo), "v"(hi));
    return r;
}
__device__ __forceinline__ void bf2x2(u32 p, float& a, float& b) {
    union { u32 u; float f; } va, vb;
    va.u = p << 16; vb.u = p & 0xffff0000u;
    a = va.f; b = vb.f;
}
// async global->LDS, 16B per lane; LDS dest = wave-uniform base + lane*16
__device__ __forceinline__ void ldg_lds16(const u16* g, u16* l) {
    __builtin_amdgcn_global_load_lds((const __attribute__((address_space(1))) u32*)g,
                                     (__attribute__((address_space(3))) u32*)l, 16, 0, 0);
}

// ---- K_PRE: weight-reorder + border-zero + transpose.
// Transpose READ now full-line coalesced: 16 lanes cover one 256B channel-row
// (4 rows/wave contiguous) instead of 4 lanes/row x 16 scattered rows.
__global__ __launch_bounds__(256) void k_pre(const float* __restrict__ w, const float* __restrict__ w_off,
                                             const float* __restrict__ x,
                                             u16* __restrict__ W2r, u16* __restrict__ Woff2,
                                             u16* __restrict__ xT) {
    __shared__ __align__(16) float SH[4608];   // prep uses 2304; transpose uses 64x72
    int bx = blockIdx.x;
    int t = threadIdx.x;
    if (bx < 256) {
        int o = bx;
        const float* src = w + (size_t)o * 2304;
#pragma unroll
        for (int j = 0; j < 9; ++j) SH[j * 256 + t] = src[j * 256 + t];
        __syncthreads();
        u16* dst = W2r + (size_t)o * 2304;
#pragma unroll
        for (int k = 0; k < 9; ++k) dst[k * 256 + t] = f2bf(SH[t * 9 + k]);   // stride-9: conflict-free
    } else if (bx == 256) {
        for (int o2 = 0; o2 < 32; ++o2) {
            if (o2 < 18) {
                const float* src = w_off + (size_t)o2 * 2304;
#pragma unroll
                for (int j = 0; j < 9; ++j) SH[j * 256 + t] = src[j * 256 + t];
                __syncthreads();
#pragma unroll
                for (int k = 0; k < 9; ++k) Woff2[(size_t)o2 * 2304 + k * 256 + t] = f2bf(SH[t * 9 + k]);
                __syncthreads();
            } else {
#pragma unroll
                for (int k = 0; k < 9; ++k) Woff2[(size_t)o2 * 2304 + k * 256 + t] = 0;
            }
        }
    } else if (bx < 777) {
        // border zero: 2080 positions, 4 per block (64 lanes each)
        int idx = (bx - 257) * 4 + (t >> 6);
        int b = idx / 260, m = idx - b * 260;
        int y, xx;
        if (m < 66)       { y = 0;  xx = m; }
        else if (m < 132) { y = 65; xx = m - 66; }
        else if (m < 196) { y = m - 132 + 1; xx = 0; }
        else              { y = m - 196 + 1; xx = 65; }
        u16* p = xT + ((size_t)(b * HP + y) * HP + xx) * CCH + (t & 63) * 4;
        uint2 zz; zz.x = 0; zz.y = 0;
        *(uint2*)p = zz;
    } else {
        int idx = bx - 777;               // 2048 transpose tiles
        int b = idx & 7;                  // XCD pin
        int r = idx >> 3;
        int y = r & 63, c0 = (r >> 6) * 64;
        {
            int rrow = t >> 4, rlane = t & 15;   // 16 lanes span one 256B row; 4 rows/wave
#pragma unroll
            for (int k = 0; k < 4; ++k) {
                int i = rrow + k * 16;           // channel 0..63
                const float* src = x + (((size_t)(b * CCH + c0 + i) * HH + y) * WW) + rlane * 4;
                float4 v = *(const float4*)src;
                *(float4*)&SH[i * 72 + rlane * 4] = v;
            }
        }
        __syncthreads();
        {
            int xc = t >> 2, cs = t & 3;   // x-position xc, 16-channel segment cs
            u16* dst = xT + (((size_t)(b * HP + y + 1) * HP) + (xc + 1)) * CCH + c0 + cs * 16;
            u32 p[8];
#pragma unroll
            for (int j = 0; j < 8; ++j)
                p[j] = pk2(SH[(cs * 16 + 2 * j) * 72 + xc], SH[(cs * 16 + 2 * j + 1) * 72 + xc]);
            uint4 d0, d1;
            d0.x = p[0]; d0.y = p[1]; d0.z = p[2]; d0.w = p[3];
            d1.x = p[4]; d1.y = p[5]; d1.z = p[6]; d1.w = p[7];
            *(uint4*)dst = d0;
            *(uint4*)(dst + 8) = d1;
        }
    }
}

// ---- K2: offset conv GEMM, K-split by tap (R4-verified; 8 blocks/CU TLP) ----
__global__ __launch_bounds__(256) void k_offconv(const u16* __restrict__ xT,
                                                 const u16* __restrict__ Woff2,
                                                 float* __restrict__ P) {
    __shared__ __align__(16) u16 AS[2][2048];
    __shared__ __align__(16) u16 BS[2][8192];
    int b = blockIdx.x, k9 = blockIdx.y;
    int pos0 = blockIdx.z * 128;
    int ky = k9 / 3, kx = k9 % 3;
    int t = threadIdx.x, lane = t & 63, wv = t >> 6;

    int srow = lane >> 3;
    int sw8 = ((lane & 7) ^ srow) << 3;
    const u16* pA = Woff2 + (size_t)k9 * 256;
    const u16* pXb = xT + (size_t)b * HP * HP * CCH;

    f32x4 acc[2][2];
    f32x4 z = {0.f, 0.f, 0.f, 0.f};
    acc[0][0] = z; acc[0][1] = z; acc[1][0] = z; acc[1][1] = z;

    auto stage = [&](int cs, int d) {
        int koff = cs * 64;
        {
            int row = wv * 8 + srow;
            ldg_lds16(pA + (size_t)row * KTOT + koff + sw8, &AS[d][wv * 512]);
        }
#pragma unroll
        for (int i = 0; i < 4; ++i) {
            int inst = wv * 4 + i;
            int rowg = pos0 + inst * 8 + srow;
            int py_ = rowg >> 6, px_ = rowg & 63;
            const u16* g = pXb + (((size_t)(py_ + ky) * HP) + px_ + kx) * CCH + koff + sw8;
            ldg_lds16(g, &BS[d][inst * 512]);
        }
    };

    stage(0, 0);
    __syncthreads();

    int buf = 0;
    int m = lane & 15, q = lane >> 4, key = lane & 7;
    for (int cs = 0; cs < 4; ++cs) {
        if (cs < 3) stage(cs + 1, buf ^ 1);
#pragma unroll
        for (int j = 0; j < 2; ++j) {
            int slot8 = (((j * 4 + q) ^ key) << 3);
            short8 a0 = *(const short8*)&AS[buf][m * 64 + slot8];
            short8 a1 = *(const short8*)&AS[buf][(16 + m) * 64 + slot8];
            short8 b0 = *(const short8*)&BS[buf][(wv * 32 + m) * 64 + slot8];
            short8 b1 = *(const short8*)&BS[buf][(wv * 32 + 16 + m) * 64 + slot8];
            acc[0][0] = __builtin_amdgcn_mfma_f32_16x16x32_bf16(a0, b0, acc[0][0], 0, 0, 0);
            acc[0][1] = __builtin_amdgcn_mfma_f32_16x16x32_bf16(a0, b1, acc[0][1], 0, 0, 0);
            acc[1][0] = __builtin_amdgcn_mfma_f32_16x16x32_bf16(a1, b0, acc[1][0], 0, 0, 0);
            acc[1][1] = __builtin_amdgcn_mfma_f32_16x16x32_bf16(a1, b1, acc[1][1], 0, 0, 0);
        }
        __syncthreads();
        buf ^= 1;
    }
    int nn = lane & 15;
    float* Pp = P + (size_t)(b * 9 + k9) * 18 * NPOS;
#pragma unroll
    for (int ao = 0; ao < 2; ++ao)
#pragma unroll
        for (int bn = 0; bn < 2; ++bn) {
            int pos = pos0 + wv * 32 + bn * 16 + nn;
#pragma unroll
            for (int r = 0; r < 4; ++r) {
                int o = ao * 16 + q * 4 + r;
                if (o < 18) Pp[o * NPOS + pos] = acc[ao][bn][r];
            }
        }
}

// ---- K2b: reduce 9 tap-partials + bias -> off2. REGRIDDED: (8,64) x 64 threads =
// 512 blocks = 2/CU (old 128 blocks left half the CUs idle). Same per-thread work.
__global__ __launch_bounds__(64) void k_reduce(const float* __restrict__ P,
                                               const float* __restrict__ b_off,
                                               float2* __restrict__ off2) {
    int b = blockIdx.x;
    int pos = blockIdx.y * 64 + threadIdx.x;
    float s[18];
#pragma unroll
    for (int o = 0; o < 18; ++o) s[o] = b_off[o];
    const float* Pp = P + (size_t)(b * 9) * 18 * NPOS + pos;
    for (int k9 = 0; k9 < 9; ++k9) {
#pragma unroll
        for (int o = 0; o < 18; ++o)
            s[o] += Pp[(k9 * 18 + o) * NPOS];
    }
#pragma unroll
    for (int op = 0; op < 9; ++op) {
        float2 v; v.x = s[2 * op]; v.y = s[2 * op + 1];
        off2[(((size_t)(b * 9 + op)) << 12) + pos] = v;
    }
}

// ---- K4 (fused, pipelined — EXACT round-4/7 structure, verified 74.9us) ----
// Per step gs=(t9,cs): vmcnt(8) [drain A(gs)+F, keep G(gs-1)=8]; barrier;
// stageA(gs+1)->AS[cur^1] (freed by barrier); vmcnt(4) [drain G(gs-1), keep A(gs+1)];
// blend -> region (cs+3)&3 (freed by barrier); [cs==0: computeState(t9+1)];
// [cs==3: prefetch off2(t9+2)]; gather region cs (tap t9+1); MFMA(gs); lgkmcnt(0).
__global__ __launch_bounds__(512, 2) void k_gemm(const u16* __restrict__ xT,
                                                 const float2* __restrict__ off2,
                                                 const u16* __restrict__ W2r,
                                                 const float* __restrict__ bias,
                                                 float* __restrict__ out) {
    __shared__ __align__(16) u16 AS[2][16384];   // 2 x [256 row][64 k] swizzled chunks, 32KB each
    __shared__ __align__(16) u16 BSF[128 * 264]; // [128 pos][256 k + 8 pad], 67.6KB
    int b = blockIdx.x;                          // batch; linear%8==b -> XCD-pinned, xT L2-hot
    int pos0 = blockIdx.z * 128;
    int t = threadIdx.x, lane = t & 63, wv = t >> 6;   // wv 0..7
    int wr = wv >> 1, wc = wv & 1;                     // 4M x 2N wave grid

    int srow = lane >> 3;
    int sw8 = ((lane & 7) ^ srow) << 3;          // A-side pre-swizzled global chunk
    const u16* pA = W2r;

    int brow0 = t >> 3;                          // 0..63
    int bcl = (t & 7) << 3;                      // 0..56 (u16 elems)
    int bbase = b * HP * HP;

    f32x4 acc[4][4];
    f32x4 z = {0.f, 0.f, 0.f, 0.f};
#pragma unroll
    for (int i = 0; i < 4; ++i)
#pragma unroll
        for (int j = 0; j < 4; ++j) acc[i][j] = z;

    auto stageA = [&](int gs, int d) {           // A slice for step gs
        int k9 = gs >> 2, cs = gs & 3;
        int koffA = k9 * 256 + cs * 64;
#pragma unroll
        for (int i = 0; i < 4; ++i) {
            int inst = wv * 4 + i;
            int row = inst * 8 + srow;           // 0..255
            ldg_lds16(pA + (size_t)row * KTOT + koffA + sw8, &AS[d][inst * 512]);
        }
    };

    // pipeline state
    const u16* gp[2][4];
    float wt[2][4];
    float2 fnext[2];
    uint4 gv[8];

    auto computeState = [&](int tap) {
#pragma unroll
        for (int ii = 0; ii < 2; ++ii) {
            int pos = pos0 + brow0 + (ii << 6);
            int y = pos >> 6, x = pos & 63;
            int ky = tap / 3, kx = tap - (tap / 3) * 3;
            float pyf = (float)(y - 1 + ky) + fnext[ii].x;
            float pxf = (float)(x - 1 + kx) + fnext[ii].y;
            float y0f = floorf(pyf), x0f = floorf(pxf);
            int y0 = (int)y0f, x0 = (int)x0f;
            int y1 = y0 + 1, x1 = x0 + 1;
            float wy1 = pyf - y0f, wy0 = 1.f - wy1;
            float wx1 = pxf - x0f, wx0 = 1.f - wx1;
            bool vy0 = (y0 >= 0) & (y0 < HH), vy1 = (y1 >= 0) & (y1 < HH);
            bool vx0 = (x0 >= 0) & (x0 < WW), vx1 = (x1 >= 0) & (x1 < WW);
            int yc0 = min(max(y0, 0), HH - 1), yc1 = min(max(y1, 0), HH - 1);
            int xc0 = min(max(x0, 0), WW - 1), xc1 = min(max(x1, 0), WW - 1);
            wt[ii][0] = (vy0 & vx0) ? wy0 * wx0 : 0.f;
            wt[ii][1] = (vy0 & vx1) ? wy0 * wx1 : 0.f;
            wt[ii][2] = (vy1 & vx0) ? wy1 * wx0 : 0.f;
            wt[ii][3] = (vy1 & vx1) ? wy1 * wx1 : 0.f;
            gp[ii][0] = xT + (size_t)(bbase + (yc0 + 1) * HP + xc0 + 1) * CCH + bcl;
            gp[ii][1] = xT + (size_t)(bbase + (yc0 + 1) * HP + xc1 + 1) * CCH + bcl;
            gp[ii][2] = xT + (size_t)(bbase + (yc1 + 1) * HP + xc0 + 1) * CCH + bcl;
            gp[ii][3] = xT + (size_t)(bbase + (yc1 + 1) * HP + xc1 + 1) * CCH + bcl;
        }
    };
    auto gatherRegion = [&](int rr) {
#pragma unroll
        for (int ii = 0; ii < 2; ++ii)
#pragma unroll
            for (int c = 0; c < 4; ++c)
                gv[ii * 4 + c] = *(const uint4*)(gp[ii][c] + rr * 64);
    };
    auto blendWrite = [&](int rr) {
#pragma unroll
        for (int ii = 0; ii < 2; ++ii) {
            int row = brow0 + (ii << 6);
            float v[8];
#pragma unroll
            for (int dw = 0; dw < 4; ++dw) {
                float a0, b0_, a1, b1_, a2, b2_, a3, b3_;
                bf2x2(((const u32*)&gv[ii * 4 + 0])[dw], a0, b0_);
                bf2x2(((const u32*)&gv[ii * 4 + 1])[dw], a1, b1_);
                bf2x2(((const u32*)&gv[ii * 4 + 2])[dw], a2, b2_);
                bf2x2(((const u32*)&gv[ii * 4 + 3])[dw], a3, b3_);
                v[2 * dw]     = wt[ii][0] * a0 + wt[ii][1] * a1 + wt[ii][2] * a2 + wt[ii][3] * a3;
                v[2 * dw + 1] = wt[ii][0] * b0_ + wt[ii][1] * b1_ + wt[ii][2] * b2_ + wt[ii][3] * b3_;
            }
            uint4 sv;
            sv.x = cvtpk(v[0], v[1]); sv.y = cvtpk(v[2], v[3]);
            sv.z = cvtpk(v[4], v[5]); sv.w = cvtpk(v[6], v[7]);
            *(uint4*)&BSF[row * 264 + rr * 64 + bcl] = sv;
        }
    };

    // ---- prologue: fill all 4 regions of tap 0 (sync); prefetch off2(1); issue A(0) ----
    {
        fnext[0] = off2[((size_t)(b * 9 + 0) << 12) + pos0 + brow0];
        fnext[1] = off2[((size_t)(b * 9 + 0) << 12) + pos0 + brow0 + 64];
        computeState(0);
#pragma unroll
        for (int rr = 0; rr < 4; ++rr) {
            gatherRegion(rr);
            blendWrite(rr);
        }
        fnext[0] = off2[((size_t)(b * 9 + 1) << 12) + pos0 + brow0];
        fnext[1] = off2[((size_t)(b * 9 + 1) << 12) + pos0 + brow0 + 64];
        stageA(0, 0);
        asm volatile("s_waitcnt lgkmcnt(0)" ::: "memory");   // BSF(tap0) ds_writes flushed
    }

    int m = lane & 15, q = lane >> 4, key = lane & 7;
    for (int gs = 0; gs <= 35; ++gs) {
        int t9 = gs >> 2, cs = gs & 3, cur = gs & 1;
        // drain my A(gs) staging loads (oldest in FIFO); keep G(gs-1) in flight
        if (gs >= 1 && gs <= 32) { asm volatile("s_waitcnt vmcnt(8)" ::: "memory"); }
        else                     { asm volatile("s_waitcnt vmcnt(0)" ::: "memory"); }
        __builtin_amdgcn_s_barrier();            // AS[cur]+BSF(region cs) complete; prior readers done

        if (gs < 35) stageA(gs + 1, cur ^ 1);    // AS[cur^1]: last read at gs-1, freed by barrier
        __builtin_amdgcn_sched_barrier(0);       // pin FIFO order: A before G

        // blend gathers issued last iteration -> region (cs+3)&3 (last read at gs-1)
        if (gs >= 1 && gs <= 32) {
            asm volatile("s_waitcnt vmcnt(4)" ::: "memory");  // G(gs-1) landed; A(gs+1) stays in flight
            blendWrite((cs + 3) & 3);
        }
        if (cs == 0 && t9 <= 7) computeState(t9 + 1);
        if (gs <= 31) {
            if (cs == 3 && t9 <= 6) {            // prefetch off2 for tap t9+2 (used at next cs0)
                fnext[0] = off2[((size_t)(b * 9 + t9 + 2) << 12) + pos0 + brow0];
                fnext[1] = off2[((size_t)(b * 9 + t9 + 2) << 12) + pos0 + brow0 + 64];
            }
            gatherRegion(cs);                    // gathers for (tap t9+1, region cs)
        }
        __builtin_amdgcn_sched_barrier(0);       // loads issued before MFMA block

#pragma unroll
        for (int j = 0; j < 2; ++j) {
            int slot8 = (((j * 4 + q) ^ key) << 3);
            int bchunk = (cs * 8 + j * 4 + q) << 3;
            short8 af[4], bfr[4];
#pragma unroll
            for (int ao = 0; ao < 4; ++ao)
                af[ao] = *(const short8*)&AS[cur][(wr * 64 + ao * 16 + m) * 64 + slot8];
#pragma unroll
            for (int bn = 0; bn < 4; ++bn)
                bfr[bn] = *(const short8*)&BSF[(wc * 64 + bn * 16 + m) * 264 + bchunk];
            __builtin_amdgcn_s_setprio(1);
#pragma unroll
            for (int ao = 0; ao < 4; ++ao)
#pragma unroll
                for (int bn = 0; bn < 4; ++bn)
                    acc[ao][bn] = __builtin_amdgcn_mfma_f32_16x16x32_bf16(af[ao], bfr[bn], acc[ao][bn], 0, 0, 0);
            __builtin_amdgcn_s_setprio(0);
        }
        asm volatile("s_waitcnt lgkmcnt(0)" ::: "memory");  // my ds_reads+ds_writes done before next barrier
    }

    // epilogue: bias + sigmoid -> fp32 NCHW
    int nn = lane & 15;
#pragma unroll
    for (int ao = 0; ao < 4; ++ao) {
        int ob = wr * 64 + ao * 16 + q * 4;
#pragma unroll
        for (int bn = 0; bn < 4; ++bn) {
            int pos = pos0 + wc * 64 + bn * 16 + nn;
#pragma unroll
            for (int r = 0; r < 4; ++r) {
                float v = acc[ao][bn][r] + bias[ob + r];
                float sg = 1.0f / (1.0f + __expf(-v));
                out[(size_t)((b * CCH + ob + r) * NPOS) + pos] = sg;
            }
        }
    }
}

extern "C" void kernel_launch(void* const* d_in, const int* in_sizes, int n_in,
                              void* d_out, int out_size, void* d_ws, size_t ws_size,
                              hipStream_t stream) {
    const float* x     = (const float*)d_in[0];
    const float* w_off = (const float*)d_in[1];
    const float* b_off = (const float*)d_in[2];
    const float* w     = (const float*)d_in[3];
    const float* bias  = (const float*)d_in[4];
    float* out = (float*)d_out;

    char* ws = (char*)d_ws;
    u16*    xT    = (u16*)ws;
    u16*    W2r   = (u16*)(ws + W2R_OFF);
    u16*    Woff2 = (u16*)(ws + WOFF2_OFF);
    float*  P     = (float*)(ws + P_OFF);
    float2* off2  = (float2*)(ws + OFF2_OFF);

    if (ws_size < WS_MIN) return;

    k_pre<<<2825, 256, 0, stream>>>(w, w_off, x, W2r, Woff2, xT);
    k_offconv<<<dim3(8, 9, 32), 256, 0, stream>>>(xT, Woff2, P);
    k_reduce<<<dim3(8, 64), 64, 0, stream>>>(P, b_off, off2);
    k_gemm<<<dim3(8, 1, 32), 512, 0, stream>>>(xT, off2, W2r, bias, out);
}

// Round 13
// 174.758 us; speedup vs baseline: 1.1582x; 1.0487x over previous
//
#include <hip/hip_runtime.h>

typedef unsigned short u16;
typedef unsigned int u32;
typedef __attribute__((ext_vector_type(8))) short short8;
typedef __attribute__((ext_vector_type(4))) float f32x4;

#define BB 8
#define CCH 256
#define HH 64
#define WW 64
#define HP 66
#define NPOS 4096
#define KTOT 2304

// ---- ws layout (bytes) ----
#define XT_BYTES   17842176ull                 // bf16 [8][66][66][256]
#define W2R_OFF    17842176ull                 // bf16 [256][2304] row-major
#define WOFF2_OFF  19021824ull                 // bf16 [32][2304]
#define P_OFF      19169280ull                 // fp32 [8][9][18][4096] partials
#define OFF2_OFF   40402944ull                 // float2 [8][9][4096]
#define WS_MIN     42762240ull

__device__ __forceinline__ u16 f2bf(float f) {
    union { float f; u32 u; } v; v.f = f;
    u32 r = v.u + 0x7FFFu + ((v.u >> 16) & 1u);
    return (u16)(r >> 16);
}
__device__ __forceinline__ u32 pk2(float a, float b) {
    return (u32)f2bf(a) | ((u32)f2bf(b) << 16);
}
// single-instruction packed f32->bf16 (RNE, same bits as pk2 for finite values)
__device__ __forceinline__ u32 cvtpk(float lo, float hi) {
    u32 r;
    asm("v_cvt_pk_bf16_f32 %0, %1, %2" : "=v"(r) : "v"(lo), "v"(hi));
    return r;
}
__device__ __forceinline__ void bf2x2(u32 p, float& a, float& b) {
    union { u32 u; float f; } va, vb;
    va.u = p << 16; vb.u = p & 0xffff0000u;
    a = va.f; b = vb.f;
}
// async global->LDS, 16B per lane; LDS dest = wave-uniform base + lane*16
__device__ __forceinline__ void ldg_lds16(const u16* g, u16* l) {
    __builtin_amdgcn_global_load_lds((const __attribute__((address_space(1))) u32*)g,
                                     (__attribute__((address_space(3))) u32*)l, 16, 0, 0);
}

// ---- K_PRE: weight-reorder + border-zero + transpose.
// R12: Woff2 reorder PARALLELIZED across 32 blocks (was: ONE block looping 32 rows
// serially with 2 barriers/iter -> the whole kernel's tail). Blocks:
// [0,256) w-reorder | [256,288) Woff2 rows | [288,808) border | [808,2856) transpose.
__global__ __launch_bounds__(256) void k_pre(const float* __restrict__ w, const float* __restrict__ w_off,
                                             const float* __restrict__ x,
                                             u16* __restrict__ W2r, u16* __restrict__ Woff2,
                                             u16* __restrict__ xT) {
    __shared__ __align__(16) float SH[4608];   // prep uses 2304; transpose uses 64x72
    int bx = blockIdx.x;
    int t = threadIdx.x;
    if (bx < 256) {
        int o = bx;
        const float* src = w + (size_t)o * 2304;
#pragma unroll
        for (int j = 0; j < 9; ++j) SH[j * 256 + t] = src[j * 256 + t];
        __syncthreads();
        u16* dst = W2r + (size_t)o * 2304;
#pragma unroll
        for (int k = 0; k < 9; ++k) dst[k * 256 + t] = f2bf(SH[t * 9 + k]);   // stride-9: conflict-free
    } else if (bx < 288) {
        int o2 = bx - 256;                      // one block per Woff2 row (was serial loop)
        if (o2 < 18) {
            const float* src = w_off + (size_t)o2 * 2304;
#pragma unroll
            for (int j = 0; j < 9; ++j) SH[j * 256 + t] = src[j * 256 + t];
            __syncthreads();
#pragma unroll
            for (int k = 0; k < 9; ++k) Woff2[(size_t)o2 * 2304 + k * 256 + t] = f2bf(SH[t * 9 + k]);
        } else {
#pragma unroll
            for (int k = 0; k < 9; ++k) Woff2[(size_t)o2 * 2304 + k * 256 + t] = 0;
        }
    } else if (bx < 808) {
        // border zero: 2080 positions, 4 per block (64 lanes each)
        int idx = (bx - 288) * 4 + (t >> 6);
        int b = idx / 260, m = idx - b * 260;
        int y, xx;
        if (m < 66)       { y = 0;  xx = m; }
        else if (m < 132) { y = 65; xx = m - 66; }
        else if (m < 196) { y = m - 132 + 1; xx = 0; }
        else              { y = m - 196 + 1; xx = 65; }
        u16* p = xT + ((size_t)(b * HP + y) * HP + xx) * CCH + (t & 63) * 4;
        uint2 zz; zz.x = 0; zz.y = 0;
        *(uint2*)p = zz;
    } else {
        int idx = bx - 808;               // 2048 transpose tiles
        int b = idx & 7;                  // XCD pin
        int r = idx >> 3;
        int y = r & 63, c0 = (r >> 6) * 64;
        {
            int rrow = t >> 4, rlane = t & 15;   // 16 lanes span one 256B row; 4 rows/wave
#pragma unroll
            for (int k = 0; k < 4; ++k) {
                int i = rrow + k * 16;           // channel 0..63
                const float* src = x + (((size_t)(b * CCH + c0 + i) * HH + y) * WW) + rlane * 4;
                float4 v = *(const float4*)src;
                *(float4*)&SH[i * 72 + rlane * 4] = v;
            }
        }
        __syncthreads();
        {
            int xc = t >> 2, cs = t & 3;   // x-position xc, 16-channel segment cs
            u16* dst = xT + (((size_t)(b * HP + y + 1) * HP) + (xc + 1)) * CCH + c0 + cs * 16;
            u32 p[8];
#pragma unroll
            for (int j = 0; j < 8; ++j)
                p[j] = pk2(SH[(cs * 16 + 2 * j) * 72 + xc], SH[(cs * 16 + 2 * j + 1) * 72 + xc]);
            uint4 d0, d1;
            d0.x = p[0]; d0.y = p[1]; d0.z = p[2]; d0.w = p[3];
            d1.x = p[4]; d1.y = p[5]; d1.z = p[6]; d1.w = p[7];
            *(uint4*)dst = d0;
            *(uint4*)(dst + 8) = d1;
        }
    }
}

// ---- K2: offset conv GEMM, K-split by tap (R4-verified; 8 blocks/CU TLP) ----
__global__ __launch_bounds__(256) void k_offconv(const u16* __restrict__ xT,
                                                 const u16* __restrict__ Woff2,
                                                 float* __restrict__ P) {
    __shared__ __align__(16) u16 AS[2][2048];
    __shared__ __align__(16) u16 BS[2][8192];
    int b = blockIdx.x, k9 = blockIdx.y;
    int pos0 = blockIdx.z * 128;
    int ky = k9 / 3, kx = k9 % 3;
    int t = threadIdx.x, lane = t & 63, wv = t >> 6;

    int srow = lane >> 3;
    int sw8 = ((lane & 7) ^ srow) << 3;
    const u16* pA = Woff2 + (size_t)k9 * 256;
    const u16* pXb = xT + (size_t)b * HP * HP * CCH;

    f32x4 acc[2][2];
    f32x4 z = {0.f, 0.f, 0.f, 0.f};
    acc[0][0] = z; acc[0][1] = z; acc[1][0] = z; acc[1][1] = z;

    auto stage = [&](int cs, int d) {
        int koff = cs * 64;
        {
            int row = wv * 8 + srow;
            ldg_lds16(pA + (size_t)row * KTOT + koff + sw8, &AS[d][wv * 512]);
        }
#pragma unroll
        for (int i = 0; i < 4; ++i) {
            int inst = wv * 4 + i;
            int rowg = pos0 + inst * 8 + srow;
            int py_ = rowg >> 6, px_ = rowg & 63;
            const u16* g = pXb + (((size_t)(py_ + ky) * HP) + px_ + kx) * CCH + koff + sw8;
            ldg_lds16(g, &BS[d][inst * 512]);
        }
    };

    stage(0, 0);
    __syncthreads();

    int buf = 0;
    int m = lane & 15, q = lane >> 4, key = lane & 7;
    for (int cs = 0; cs < 4; ++cs) {
        if (cs < 3) stage(cs + 1, buf ^ 1);
#pragma unroll
        for (int j = 0; j < 2; ++j) {
            int slot8 = (((j * 4 + q) ^ key) << 3);
            short8 a0 = *(const short8*)&AS[buf][m * 64 + slot8];
            short8 a1 = *(const short8*)&AS[buf][(16 + m) * 64 + slot8];
            short8 b0 = *(const short8*)&BS[buf][(wv * 32 + m) * 64 + slot8];
            short8 b1 = *(const short8*)&BS[buf][(wv * 32 + 16 + m) * 64 + slot8];
            acc[0][0] = __builtin_amdgcn_mfma_f32_16x16x32_bf16(a0, b0, acc[0][0], 0, 0, 0);
            acc[0][1] = __builtin_amdgcn_mfma_f32_16x16x32_bf16(a0, b1, acc[0][1], 0, 0, 0);
            acc[1][0] = __builtin_amdgcn_mfma_f32_16x16x32_bf16(a1, b0, acc[1][0], 0, 0, 0);
            acc[1][1] = __builtin_amdgcn_mfma_f32_16x16x32_bf16(a1, b1, acc[1][1], 0, 0, 0);
        }
        __syncthreads();
        buf ^= 1;
    }
    int nn = lane & 15;
    float* Pp = P + (size_t)(b * 9 + k9) * 18 * NPOS;
#pragma unroll
    for (int ao = 0; ao < 2; ++ao)
#pragma unroll
        for (int bn = 0; bn < 2; ++bn) {
            int pos = pos0 + wv * 32 + bn * 16 + nn;
#pragma unroll
            for (int r = 0; r < 4; ++r) {
                int o = ao * 16 + q * 4 + r;
                if (o < 18) Pp[o * NPOS + pos] = acc[ao][bn][r];
            }
        }
}

// ---- K2b: reduce 9 tap-partials + bias -> off2 (R11-verified regrid: 512 blocks x 64) ----
__global__ __launch_bounds__(64) void k_reduce(const float* __restrict__ P,
                                               const float* __restrict__ b_off,
                                               float2* __restrict__ off2) {
    int b = blockIdx.x;
    int pos = blockIdx.y * 64 + threadIdx.x;
    float s[18];
#pragma unroll
    for (int o = 0; o < 18; ++o) s[o] = b_off[o];
    const float* Pp = P + (size_t)(b * 9) * 18 * NPOS + pos;
    for (int k9 = 0; k9 < 9; ++k9) {
#pragma unroll
        for (int o = 0; o < 18; ++o)
            s[o] += Pp[(k9 * 18 + o) * NPOS];
    }
#pragma unroll
    for (int op = 0; op < 9; ++op) {
        float2 v; v.x = s[2 * op]; v.y = s[2 * op + 1];
        off2[(((size_t)(b * 9 + op)) << 12) + pos] = v;
    }
}

// ---- K4 (fused, pipelined — EXACT round-4/7 structure, verified 74.9us) ----
// Per step gs=(t9,cs): vmcnt(8) [drain A(gs)+F, keep G(gs-1)=8]; barrier;
// stageA(gs+1)->AS[cur^1] (freed by barrier); vmcnt(4) [drain G(gs-1), keep A(gs+1)];
// blend -> region (cs+3)&3 (freed by barrier); [cs==0: computeState(t9+1)];
// [cs==3: prefetch off2(t9+2)]; gather region cs (tap t9+1); MFMA(gs); lgkmcnt(0).
__global__ __launch_bounds__(512, 2) void k_gemm(const u16* __restrict__ xT,
                                                 const float2* __restrict__ off2,
                                                 const u16* __restrict__ W2r,
                                                 const float* __restrict__ bias,
                                                 float* __restrict__ out) {
    __shared__ __align__(16) u16 AS[2][16384];   // 2 x [256 row][64 k] swizzled chunks, 32KB each
    __shared__ __align__(16) u16 BSF[128 * 264]; // [128 pos][256 k + 8 pad], 67.6KB
    int b = blockIdx.x;                          // batch; linear%8==b -> XCD-pinned, xT L2-hot
    int pos0 = blockIdx.z * 128;
    int t = threadIdx.x, lane = t & 63, wv = t >> 6;   // wv 0..7
    int wr = wv >> 1, wc = wv & 1;                     // 4M x 2N wave grid

    int srow = lane >> 3;
    int sw8 = ((lane & 7) ^ srow) << 3;          // A-side pre-swizzled global chunk
    const u16* pA = W2r;

    int brow0 = t >> 3;                          // 0..63
    int bcl = (t & 7) << 3;                      // 0..56 (u16 elems)
    int bbase = b * HP * HP;

    f32x4 acc[4][4];
    f32x4 z = {0.f, 0.f, 0.f, 0.f};
#pragma unroll
    for (int i = 0; i < 4; ++i)
#pragma unroll
        for (int j = 0; j < 4; ++j) acc[i][j] = z;

    auto stageA = [&](int gs, int d) {           // A slice for step gs
        int k9 = gs >> 2, cs = gs & 3;
        int koffA = k9 * 256 + cs * 64;
#pragma unroll
        for (int i = 0; i < 4; ++i) {
            int inst = wv * 4 + i;
            int row = inst * 8 + srow;           // 0..255
            ldg_lds16(pA + (size_t)row * KTOT + koffA + sw8, &AS[d][inst * 512]);
        }
    };

    // pipeline state
    const u16* gp[2][4];
    float wt[2][4];
    float2 fnext[2];
    uint4 gv[8];

    auto computeState = [&](int tap) {
#pragma unroll
        for (int ii = 0; ii < 2; ++ii) {
            int pos = pos0 + brow0 + (ii << 6);
            int y = pos >> 6, x = pos & 63;
            int ky = tap / 3, kx = tap - (tap / 3) * 3;
            float pyf = (float)(y - 1 + ky) + fnext[ii].x;
            float pxf = (float)(x - 1 + kx) + fnext[ii].y;
            float y0f = floorf(pyf), x0f = floorf(pxf);
            int y0 = (int)y0f, x0 = (int)x0f;
            int y1 = y0 + 1, x1 = x0 + 1;
            float wy1 = pyf - y0f, wy0 = 1.f - wy1;
            float wx1 = pxf - x0f, wx0 = 1.f - wx1;
            bool vy0 = (y0 >= 0) & (y0 < HH), vy1 = (y1 >= 0) & (y1 < HH);
            bool vx0 = (x0 >= 0) & (x0 < WW), vx1 = (x1 >= 0) & (x1 < WW);
            int yc0 = min(max(y0, 0), HH - 1), yc1 = min(max(y1, 0), HH - 1);
            int xc0 = min(max(x0, 0), WW - 1), xc1 = min(max(x1, 0), WW - 1);
            wt[ii][0] = (vy0 & vx0) ? wy0 * wx0 : 0.f;
            wt[ii][1] = (vy0 & vx1) ? wy0 * wx1 : 0.f;
            wt[ii][2] = (vy1 & vx0) ? wy1 * wx0 : 0.f;
            wt[ii][3] = (vy1 & vx1) ? wy1 * wx1 : 0.f;
            gp[ii][0] = xT + (size_t)(bbase + (yc0 + 1) * HP + xc0 + 1) * CCH + bcl;
            gp[ii][1] = xT + (size_t)(bbase + (yc0 + 1) * HP + xc1 + 1) * CCH + bcl;
            gp[ii][2] = xT + (size_t)(bbase + (yc1 + 1) * HP + xc0 + 1) * CCH + bcl;
            gp[ii][3] = xT + (size_t)(bbase + (yc1 + 1) * HP + xc1 + 1) * CCH + bcl;
        }
    };
    auto gatherRegion = [&](int rr) {
#pragma unroll
        for (int ii = 0; ii < 2; ++ii)
#pragma unroll
            for (int c = 0; c < 4; ++c)
                gv[ii * 4 + c] = *(const uint4*)(gp[ii][c] + rr * 64);
    };
    auto blendWrite = [&](int rr) {
#pragma unroll
        for (int ii = 0; ii < 2; ++ii) {
            int row = brow0 + (ii << 6);
            float v[8];
#pragma unroll
            for (int dw = 0; dw < 4; ++dw) {
                float a0, b0_, a1, b1_, a2, b2_, a3, b3_;
                bf2x2(((const u32*)&gv[ii * 4 + 0])[dw], a0, b0_);
                bf2x2(((const u32*)&gv[ii * 4 + 1])[dw], a1, b1_);
                bf2x2(((const u32*)&gv[ii * 4 + 2])[dw], a2, b2_);
                bf2x2(((const u32*)&gv[ii * 4 + 3])[dw], a3, b3_);
                v[2 * dw]     = wt[ii][0] * a0 + wt[ii][1] * a1 + wt[ii][2] * a2 + wt[ii][3] * a3;
                v[2 * dw + 1] = wt[ii][0] * b0_ + wt[ii][1] * b1_ + wt[ii][2] * b2_ + wt[ii][3] * b3_;
            }
            uint4 sv;
            sv.x = cvtpk(v[0], v[1]); sv.y = cvtpk(v[2], v[3]);
            sv.z = cvtpk(v[4], v[5]); sv.w = cvtpk(v[6], v[7]);
            *(uint4*)&BSF[row * 264 + rr * 64 + bcl] = sv;
        }
    };

    // ---- prologue: fill all 4 regions of tap 0 (sync); prefetch off2(1); issue A(0) ----
    {
        fnext[0] = off2[((size_t)(b * 9 + 0) << 12) + pos0 + brow0];
        fnext[1] = off2[((size_t)(b * 9 + 0) << 12) + pos0 + brow0 + 64];
        computeState(0);
#pragma unroll
        for (int rr = 0; rr < 4; ++rr) {
            gatherRegion(rr);
            blendWrite(rr);
        }
        fnext[0] = off2[((size_t)(b * 9 + 1) << 12) + pos0 + brow0];
        fnext[1] = off2[((size_t)(b * 9 + 1) << 12) + pos0 + brow0 + 64];
        stageA(0, 0);
        asm volatile("s_waitcnt lgkmcnt(0)" ::: "memory");   // BSF(tap0) ds_writes flushed
    }

    int m = lane & 15, q = lane >> 4, key = lane & 7;
    for (int gs = 0; gs <= 35; ++gs) {
        int t9 = gs >> 2, cs = gs & 3, cur = gs & 1;
        // drain my A(gs) staging loads (oldest in FIFO); keep G(gs-1) in flight
        if (gs >= 1 && gs <= 32) { asm volatile("s_waitcnt vmcnt(8)" ::: "memory"); }
        else                     { asm volatile("s_waitcnt vmcnt(0)" ::: "memory"); }
        __builtin_amdgcn_s_barrier();            // AS[cur]+BSF(region cs) complete; prior readers done

        if (gs < 35) stageA(gs + 1, cur ^ 1);    // AS[cur^1]: last read at gs-1, freed by barrier
        __builtin_amdgcn_sched_barrier(0);       // pin FIFO order: A before G

        // blend gathers issued last iteration -> region (cs+3)&3 (last read at gs-1)
        if (gs >= 1 && gs <= 32) {
            asm volatile("s_waitcnt vmcnt(4)" ::: "memory");  // G(gs-1) landed; A(gs+1) stays in flight
            blendWrite((cs + 3) & 3);
        }
        if (cs == 0 && t9 <= 7) computeState(t9 + 1);
        if (gs <= 31) {
            if (cs == 3 && t9 <= 6) {            // prefetch off2 for tap t9+2 (used at next cs0)
                fnext[0] = off2[((size_t)(b * 9 + t9 + 2) << 12) + pos0 + brow0];
                fnext[1] = off2[((size_t)(b * 9 + t9 + 2) << 12) + pos0 + brow0 + 64];
            }
            gatherRegion(cs);                    // gathers for (tap t9+1, region cs)
        }
        __builtin_amdgcn_sched_barrier(0);       // loads issued before MFMA block

#pragma unroll
        for (int j = 0; j < 2; ++j) {
            int slot8 = (((j * 4 + q) ^ key) << 3);
            int bchunk = (cs * 8 + j * 4 + q) << 3;
            short8 af[4], bfr[4];
#pragma unroll
            for (int ao = 0; ao < 4; ++ao)
                af[ao] = *(const short8*)&AS[cur][(wr * 64 + ao * 16 + m) * 64 + slot8];
#pragma unroll
            for (int bn = 0; bn < 4; ++bn)
                bfr[bn] = *(const short8*)&BSF[(wc * 64 + bn * 16 + m) * 264 + bchunk];
            __builtin_amdgcn_s_setprio(1);
#pragma unroll
            for (int ao = 0; ao < 4; ++ao)
#pragma unroll
                for (int bn = 0; bn < 4; ++bn)
                    acc[ao][bn] = __builtin_amdgcn_mfma_f32_16x16x32_bf16(af[ao], bfr[bn], acc[ao][bn], 0, 0, 0);
            __builtin_amdgcn_s_setprio(0);
        }
        asm volatile("s_waitcnt lgkmcnt(0)" ::: "memory");  // my ds_reads+ds_writes done before next barrier
    }

    // epilogue: bias + sigmoid -> fp32 NCHW
    int nn = lane & 15;
#pragma unroll
    for (int ao = 0; ao < 4; ++ao) {
        int ob = wr * 64 + ao * 16 + q * 4;
#pragma unroll
        for (int bn = 0; bn < 4; ++bn) {
            int pos = pos0 + wc * 64 + bn * 16 + nn;
#pragma unroll
            for (int r = 0; r < 4; ++r) {
                float v = acc[ao][bn][r] + bias[ob + r];
                float sg = 1.0f / (1.0f + __expf(-v));
                out[(size_t)((b * CCH + ob + r) * NPOS) + pos] = sg;
            }
        }
    }
}

extern "C" void kernel_launch(void* const* d_in, const int* in_sizes, int n_in,
                              void* d_out, int out_size, void* d_ws, size_t ws_size,
                              hipStream_t stream) {
    const float* x     = (const float*)d_in[0];
    const float* w_off = (const float*)d_in[1];
    const float* b_off = (const float*)d_in[2];
    const float* w     = (const float*)d_in[3];
    const float* bias  = (const float*)d_in[4];
    float* out = (float*)d_out;

    char* ws = (char*)d_ws;
    u16*    xT    = (u16*)ws;
    u16*    W2r   = (u16*)(ws + W2R_OFF);
    u16*    Woff2 = (u16*)(ws + WOFF2_OFF);
    float*  P     = (float*)(ws + P_OFF);
    float2* off2  = (float2*)(ws + OFF2_OFF);

    if (ws_size < WS_MIN) return;

    k_pre<<<2856, 256, 0, stream>>>(w, w_off, x, W2r, Woff2, xT);
    k_offconv<<<dim3(8, 9, 32), 256, 0, stream>>>(xT, Woff2, P);
    k_reduce<<<dim3(8, 64), 64, 0, stream>>>(P, b_off, off2);
    k_gemm<<<dim3(8, 1, 32), 512, 0, stream>>>(xT, off2, W2r, bias, out);
}